// Round 8
// baseline (221.961 us; speedup 1.0000x reference)
//
#include <hip/hip_runtime.h>

// ---------------------------------------------------------------------------
// LoRA_Attention: fold LoRA into weights; bf16 MFMA GEMMs; split-K flash
// attention (R6 skeleton + registerized relW -> 38.4 KB LDS, 4 blocks/CU,
// single dispatch round); BK=64 QKV GEMM; fused convert+fold. exp2 softmax,
// no-max (scores bounded). XCD-swizzled attn grid.
// ---------------------------------------------------------------------------

#define DIM   768
#define HEADS 12
#define HD    64
#define NTOK  2304
#define RANK  8
#define GRD   48
#define CHUNKS 4
#define LOG2E 1.44269504088896f

typedef __attribute__((ext_vector_type(8))) short bf16x8;
typedef __attribute__((ext_vector_type(4))) float f32x4;
typedef unsigned short ushort_t;

__device__ __forceinline__ unsigned short f2bf(float x) {
    union { float f; unsigned u; } v; v.f = x;
    unsigned r = v.u + 0x7fffu + ((v.u >> 16) & 1u);
    return (unsigned short)(r >> 16);
}
__device__ __forceinline__ float bf2f(unsigned short h) {
    return __uint_as_float(((unsigned)h) << 16);
}
__device__ __forceinline__ void gload_lds16(const ushort_t* g, ushort_t* l) {
    __builtin_amdgcn_global_load_lds(
        (const __attribute__((address_space(1))) unsigned int*)g,
        (__attribute__((address_space(3))) unsigned int*)l, 16, 0, 0);
}

// ---------------------------------------------------------------------------
// k_prep: fold LoRA into transposed weights (all 2304 blocks) + convert
// x / rel tables to bf16 (blocks < 1740). Independent tasks, one launch.
// ---------------------------------------------------------------------------
__global__ __launch_bounds__(256) void k_prep(
    const float* __restrict__ x, ushort_t* __restrict__ xb,
    const float* __restrict__ rph, const float* __restrict__ rpw,
    ushort_t* __restrict__ rphb, ushort_t* __restrict__ rpwb,
    const float* __restrict__ Wq, const float* __restrict__ Wk,
    const float* __restrict__ Wv, const float* __restrict__ Wp,
    const float* __restrict__ Aq, const float* __restrict__ Bq,
    const float* __restrict__ Ak, const float* __restrict__ Bk,
    const float* __restrict__ Av, const float* __restrict__ Bv,
    ushort_t* __restrict__ WT) {
    int bid = blockIdx.x, tid = threadIdx.x;

    // convert task
    if (bid < 1740) {
        if (bid < 1728) {
            int idx = (bid * 256 + tid) * 4;
            float4 v = *(const float4*)(x + idx);
            ushort4 o = make_ushort4(f2bf(v.x), f2bf(v.y), f2bf(v.z), f2bf(v.w));
            *(ushort4*)(xb + idx) = o;
        } else {
            int e = ((bid - 1728) * 256 + tid) * 4;
            const int TSZ = (2 * GRD - 1) * HD;   // 6080
            if (e < TSZ) {
                float4 v = *(const float4*)(rph + e);
                ushort4 o = make_ushort4(f2bf(v.x), f2bf(v.y), f2bf(v.z), f2bf(v.w));
                *(ushort4*)(rphb + e) = o;
            } else if (e < 2 * TSZ) {
                float4 v = *(const float4*)(rpw + e - TSZ);
                ushort4 o = make_ushort4(f2bf(v.x), f2bf(v.y), f2bf(v.z), f2bf(v.w));
                *(ushort4*)(rpwb + e - TSZ) = o;
            }
        }
    }

    // fold task
    int kb = (bid % 24) * 32;
    int nb = (bid / 24) * 32;
    int sel = nb / DIM, nmod = nb % DIM;
    const float* W = (sel == 0) ? Wq : (sel == 1) ? Wk : (sel == 2) ? Wv : Wp;
    const float* A = (sel == 0) ? Aq : (sel == 1) ? Ak : Av;
    const float* B = (sel == 0) ? Bq : (sel == 1) ? Bk : Bv;
    __shared__ float T[32][33];
    for (int i = tid; i < 1024; i += 256) {
        int kl = i >> 5, nl = i & 31;
        float v = W[(kb + kl) * DIM + nmod + nl];
        if (sel < 3) {
            #pragma unroll
            for (int r = 0; r < RANK; r++)
                v += A[(kb + kl) * RANK + r] * B[r * DIM + nmod + nl];
        }
        T[kl][nl] = v;
    }
    __syncthreads();
    for (int i = tid; i < 1024; i += 256) {
        int nl = i >> 5, kl = i & 31;
        WT[(size_t)(nb + nl) * DIM + kb + kl] = f2bf(T[kl][nl]);
    }
}

// ---------------------------------------------------------------------------
// QKV GEMM: 128x128 tile, BK=64 (12 barrier pairs instead of 24),
// global_load_lds width-16 DMA staging, 2x2 waves of 64x64.
// ---------------------------------------------------------------------------
__global__ __launch_bounds__(256) void k_gemm_qkv(
    const ushort_t* __restrict__ xb, const ushort_t* __restrict__ WT,
    const float* __restrict__ bq, const float* __restrict__ bk,
    const float* __restrict__ bv,
    ushort_t* __restrict__ Qb, ushort_t* __restrict__ Kb,
    ushort_t* __restrict__ Vtb) {
    __shared__ __align__(16) ushort_t As[128 * 64];
    __shared__ __align__(16) ushort_t Bs[128 * 64];
    int tid = threadIdx.x;
    int wave = tid >> 6, lane = tid & 63, quad = lane >> 4, l16 = lane & 15;
    int wx = wave & 1, wy = wave >> 1;
    int nb = blockIdx.x * 128, mb = blockIdx.y * 128;

    f32x4 zero = {0.f, 0.f, 0.f, 0.f};
    f32x4 acc[4][4];
    #pragma unroll
    for (int i = 0; i < 4; i++)
        #pragma unroll
        for (int j = 0; j < 4; j++) acc[i][j] = zero;

    int rl = lane >> 3;            // 0..7
    int cl = (lane & 7) * 8;       // element col within 64
    const ushort_t* gA = xb + (size_t)(mb + wave * 32 + rl) * DIM + cl;
    const ushort_t* gB = WT + (size_t)(nb + wave * 32 + rl) * DIM + cl;
    ushort_t* lA = &As[(wave * 32) * 64];   // HW adds lane*16B
    ushort_t* lB = &Bs[(wave * 32) * 64];

    for (int k0 = 0; k0 < DIM; k0 += 64) {
        __syncthreads();
        #pragma unroll
        for (int c = 0; c < 4; c++) {
            gload_lds16(gA + k0 + c * 8 * DIM, lA + c * 8 * 64);
            gload_lds16(gB + k0 + c * 8 * DIM, lB + c * 8 * 64);
        }
        __syncthreads();
        #pragma unroll
        for (int kk = 0; kk < 2; kk++) {
            bf16x8 af[4], bf[4];
            #pragma unroll
            for (int i = 0; i < 4; i++)
                af[i] = *(const bf16x8*)&As[(wy * 64 + i * 16 + l16) * 64 + kk * 32 + quad * 8];
            #pragma unroll
            for (int j = 0; j < 4; j++)
                bf[j] = *(const bf16x8*)&Bs[(wx * 64 + j * 16 + l16) * 64 + kk * 32 + quad * 8];
            #pragma unroll
            for (int i = 0; i < 4; i++)
                #pragma unroll
                for (int j = 0; j < 4; j++)
                    acc[i][j] = __builtin_amdgcn_mfma_f32_16x16x32_bf16(af[i], bf[j], acc[i][j], 0, 0, 0);
        }
    }

    #pragma unroll
    for (int j = 0; j < 4; j++) {
        int col = nb + wx * 64 + j * 16 + l16;
        int sel = col / DIM, rem = col % DIM;
        int hh = rem >> 6, cc = rem & 63;
        const float* bias = (sel == 0) ? bq : (sel == 1) ? bk : bv;
        float bval = bias[rem];
        #pragma unroll
        for (int i = 0; i < 4; i++) {
            #pragma unroll
            for (int r = 0; r < 4; r++) {
                int row = mb + wy * 64 + i * 16 + quad * 4 + r;
                unsigned short o = f2bf(acc[i][j][r] + bval);
                if (sel == 0)      Qb[(size_t)(hh * NTOK + row) * HD + cc] = o;
                else if (sel == 1) Kb[(size_t)(hh * NTOK + row) * HD + cc] = o;
                else               Vtb[(size_t)(hh * HD + cc) * NTOK + row] = o;
            }
        }
    }
}

// ---------------------------------------------------------------------------
// Rel-pos bias via MFMA (outputs pre-scaled by log2 e).
// ---------------------------------------------------------------------------
__global__ __launch_bounds__(256) void k_relmm(
    const ushort_t* __restrict__ Qb, const ushort_t* __restrict__ rphb,
    const ushort_t* __restrict__ rpwb, float* __restrict__ relH,
    float* __restrict__ relW) {
    int id = blockIdx.x * 4 + (threadIdx.x >> 6);
    int lane = threadIdx.x & 63, quad = lane >> 4, l16 = lane & 15;
    bool isW = id >= 576;
    int t = isW ? id - 576 : id;
    int h = t / GRD, g = t % GRD;
    const ushort_t* tab = isW ? rpwb : rphb;
    float* outp = isW ? relW : relH;

    f32x4 zero = {0.f, 0.f, 0.f, 0.f};
    f32x4 acc[3][3];
    #pragma unroll
    for (int i = 0; i < 3; i++)
        #pragma unroll
        for (int j = 0; j < 3; j++) acc[i][j] = zero;

    bf16x8 bfr[3][2];
    #pragma unroll
    for (int ct = 0; ct < 3; ct++) {
        int trow = g + 47 - (ct * 16 + l16);
        bfr[ct][0] = *(const bf16x8*)&tab[(size_t)trow * HD + quad * 8];
        bfr[ct][1] = *(const bf16x8*)&tab[(size_t)trow * HD + 32 + quad * 8];
    }
    #pragma unroll
    for (int ms = 0; ms < 3; ms++) {
        int m = ms * 16 + l16;
        int n = isW ? m * GRD + g : g * GRD + m;
        bf16x8 a0 = *(const bf16x8*)&Qb[(size_t)(h * NTOK + n) * HD + quad * 8];
        bf16x8 a1 = *(const bf16x8*)&Qb[(size_t)(h * NTOK + n) * HD + 32 + quad * 8];
        #pragma unroll
        for (int ct = 0; ct < 3; ct++) {
            acc[ms][ct] = __builtin_amdgcn_mfma_f32_16x16x32_bf16(a0, bfr[ct][0], acc[ms][ct], 0, 0, 0);
            acc[ms][ct] = __builtin_amdgcn_mfma_f32_16x16x32_bf16(a1, bfr[ct][1], acc[ms][ct], 0, 0, 0);
        }
    }
    #pragma unroll
    for (int ms = 0; ms < 3; ms++) {
        #pragma unroll
        for (int ct = 0; ct < 3; ct++) {
            #pragma unroll
            for (int r = 0; r < 4; r++) {
                int m = ms * 16 + quad * 4 + r;
                int n = isW ? m * GRD + g : g * GRD + m;
                int col = ct * 16 + l16;
                outp[(size_t)(h * NTOK + n) * GRD + col] = acc[ms][ct][r] * LOG2E;
            }
        }
    }
}

// ---------------------------------------------------------------------------
// Flash attention, split-K. Block = (128 q-rows, head, chunk of 576 keys).
// Grid x = h*4+chunk (XCD-local K/V sharing). R6 staging (coalesced uint4
// reg-prefetch -> stride-68 LDS), S^T compute core, registerized relW
// (kw0 = 16*((kt+ks)%3)+4*quad -> 3 uint2/strip in regs). 38.4 KB LDS ->
// 4 blocks/CU, 864 blocks fit one dispatch round.
// ---------------------------------------------------------------------------
__global__ __launch_bounds__(256, 4) void k_attn(
    const ushort_t* __restrict__ Qb, const ushort_t* __restrict__ Kb,
    const ushort_t* __restrict__ Vtb, const float* __restrict__ relH,
    const float* __restrict__ relW, float* __restrict__ Opart,
    float* __restrict__ Lpart) {
    int h = blockIdx.x >> 2, chunk = blockIdx.x & 3, qt = blockIdx.y;
    int tid = threadIdx.x;
    int wave = tid >> 6, lane = tid & 63, quad = lane >> 4, l16 = lane & 15;
    int qbase = qt * 128;
    int kbase = chunk * 576;

    __shared__ __align__(16) ushort_t Ks[64 * 68];      //  8704 B
    __shared__ __align__(16) ushort_t Vs[64 * 68];      //  8704 B
    __shared__ __align__(16) ushort_t Ps[4][32 * 68];   // 17408 B
    __shared__ __align__(16) ushort_t rhs[128 * 14];    //  3584 B  (38.4 KB total)

    // stage rel_h (12 kh of this chunk), bf16
    for (int i = tid; i < 128 * 12; i += 256) {
        int r = i / 12, c = i % 12;
        rhs[r * 14 + c] = f2bf(relH[(size_t)(h * NTOK + qbase + r) * GRD + chunk * 12 + c]);
    }

    // Q B-fragments (wave owns 32 rows = 2 strips)
    bf16x8 qf[2][2];
    #pragma unroll
    for (int s = 0; s < 2; s++) {
        int qrow = qbase + wave * 32 + s * 16 + l16;
        qf[s][0] = *(const bf16x8*)&Qb[(size_t)(h * NTOK + qrow) * HD + quad * 8];
        qf[s][1] = *(const bf16x8*)&Qb[(size_t)(h * NTOK + qrow) * HD + 32 + quad * 8];
    }
    // registerized relW: packed bf16 pairs for kw0 = m3*16 + quad*4
    uint2 rwreg[2][3];
    #pragma unroll
    for (int s = 0; s < 2; s++) {
        int row = qbase + wave * 32 + s * 16 + l16;
        const float* rp = relW + (size_t)(h * NTOK + row) * GRD + quad * 4;
        #pragma unroll
        for (int m3 = 0; m3 < 3; m3++) {
            float4 rw = *(const float4*)(rp + m3 * 16);
            uint2 u;
            u.x = (unsigned)f2bf(rw.x) | ((unsigned)f2bf(rw.y) << 16);
            u.y = (unsigned)f2bf(rw.z) | ((unsigned)f2bf(rw.w) << 16);
            rwreg[s][m3] = u;
        }
    }

    int r0 = tid >> 3, c0 = (tid & 7) * 8;
    const ushort_t* kg0 = Kb + (size_t)(h * NTOK + r0) * HD + c0;
    const ushort_t* kg1 = Kb + (size_t)(h * NTOK + r0 + 32) * HD + c0;
    const ushort_t* vg0 = Vtb + (size_t)(h * HD + r0) * NTOK + c0;
    const ushort_t* vg1 = Vtb + (size_t)(h * HD + r0 + 32) * NTOK + c0;
    int sk0 = r0 * 68 + c0, sk1 = sk0 + 32 * 68;

    float lacc[2] = {0.f, 0.f};
    f32x4 zero = {0.f, 0.f, 0.f, 0.f};
    f32x4 oacc[2][4];
    #pragma unroll
    for (int s = 0; s < 2; s++)
        #pragma unroll
        for (int cs = 0; cs < 4; cs++) oacc[s][cs] = zero;

    const float scale2 = 0.125f * LOG2E;

    uint4 rk0 = *(const uint4*)(kg0 + (size_t)kbase * HD);
    uint4 rk1 = *(const uint4*)(kg1 + (size_t)kbase * HD);
    uint4 rv0 = *(const uint4*)(vg0 + kbase);
    uint4 rv1 = *(const uint4*)(vg1 + kbase);

    for (int kt = 0; kt < 9; kt++) {
        int kb = kbase + kt * 64;
        __syncthreads();                 // all waves done reading prev K/V tile
        *(uint4*)&Ks[sk0] = rk0;  *(uint4*)&Ks[sk1] = rk1;
        *(uint4*)&Vs[sk0] = rv0;  *(uint4*)&Vs[sk1] = rv1;
        __syncthreads();
        if (kt < 8) {                    // issue next tile's loads
            int kbn = kb + 64;
            rk0 = *(const uint4*)(kg0 + (size_t)kbn * HD);
            rk1 = *(const uint4*)(kg1 + (size_t)kbn * HD);
            rv0 = *(const uint4*)(vg0 + kbn);
            rv1 = *(const uint4*)(vg1 + kbn);
        }

        // QK^T (S^T: D[m=key][n=qrow]) + softmax + packed P store, per 16-key grp
        #pragma unroll
        for (int ks = 0; ks < 4; ks++) {
            bf16x8 kf0 = *(const bf16x8*)&Ks[(ks * 16 + l16) * 68 + quad * 8];
            bf16x8 kf1 = *(const bf16x8*)&Ks[(ks * 16 + l16) * 68 + 32 + quad * 8];
            f32x4 st[2];
            #pragma unroll
            for (int s = 0; s < 2; s++) {
                f32x4 z = zero;
                z = __builtin_amdgcn_mfma_f32_16x16x32_bf16(kf0, qf[s][0], z, 0, 0, 0);
                z = __builtin_amdgcn_mfma_f32_16x16x32_bf16(kf1, qf[s][1], z, 0, 0, 0);
                st[s] = z;
            }
            int kb4 = kb + ks * 16 + quad * 4;
            int khl = kb4 / 48 - chunk * 12;      // uniform per 16-key group
            int m3 = (kt + ks) % 3;               // lane-uniform
            #pragma unroll
            for (int s = 0; s < 2; s++) {
                int row = wave * 32 + s * 16 + l16;
                float rh = bf2f(rhs[row * 14 + khl]);
                uint2 u = (m3 == 0) ? rwreg[s][0] : (m3 == 1) ? rwreg[s][1] : rwreg[s][2];
                float p0 = __builtin_amdgcn_exp2f(st[s][0] * scale2 + rh + __uint_as_float(u.x << 16));
                float p1 = __builtin_amdgcn_exp2f(st[s][1] * scale2 + rh + __uint_as_float(u.x & 0xffff0000u));
                float p2 = __builtin_amdgcn_exp2f(st[s][2] * scale2 + rh + __uint_as_float(u.y << 16));
                float p3 = __builtin_amdgcn_exp2f(st[s][3] * scale2 + rh + __uint_as_float(u.y & 0xffff0000u));
                lacc[s] += (p0 + p1) + (p2 + p3);
                uint2 w;
                w.x = __builtin_amdgcn_perm(__float_as_uint(p1), __float_as_uint(p0), 0x07060302u);
                w.y = __builtin_amdgcn_perm(__float_as_uint(p3), __float_as_uint(p2), 0x07060302u);
                *(uint2*)&Ps[wave][(s * 16 + l16) * 68 + ks * 16 + quad * 4] = w;
            }
        }

        // PV: A[m=qrow][k=key] b128 from own Ps; B[k=key][n=c] b128 from Vs
        bf16x8 vf[4][2];
        #pragma unroll
        for (int cs = 0; cs < 4; cs++) {
            vf[cs][0] = *(const bf16x8*)&Vs[(cs * 16 + l16) * 68 + quad * 8];
            vf[cs][1] = *(const bf16x8*)&Vs[(cs * 16 + l16) * 68 + 32 + quad * 8];
        }
        #pragma unroll
        for (int s = 0; s < 2; s++) {
            bf16x8 pa0 = *(const bf16x8*)&Ps[wave][(s * 16 + l16) * 68 + quad * 8];
            bf16x8 pa1 = *(const bf16x8*)&Ps[wave][(s * 16 + l16) * 68 + 32 + quad * 8];
            #pragma unroll
            for (int cs = 0; cs < 4; cs++) {
                oacc[s][cs] = __builtin_amdgcn_mfma_f32_16x16x32_bf16(pa0, vf[cs][0], oacc[s][cs], 0, 0, 0);
                oacc[s][cs] = __builtin_amdgcn_mfma_f32_16x16x32_bf16(pa1, vf[cs][1], oacc[s][cs], 0, 0, 0);
            }
        }
    }

    // l: reduce over quads (keys split across quads)
    #pragma unroll
    for (int s = 0; s < 2; s++) {
        float l = lacc[s];
        l += __shfl_xor(l, 16);
        l += __shfl_xor(l, 32);
        lacc[s] = l;
    }

    // write partials: Opart [chunk][h][tok][c], Lpart [chunk][h][tok]
    size_t obase = (size_t)(chunk * HEADS + h) * NTOK;
    #pragma unroll
    for (int s = 0; s < 2; s++) {
        #pragma unroll
        for (int cs = 0; cs < 4; cs++) {
            #pragma unroll
            for (int r = 0; r < 4; r++) {
                int row = qbase + wave * 32 + s * 16 + quad * 4 + r;
                Opart[(obase + row) * HD + cs * 16 + l16] = oacc[s][cs][r];
            }
        }
        if (quad == 0)
            Lpart[obase + qbase + wave * 32 + s * 16 + l16] = lacc[s];
    }
}

// ---------------------------------------------------------------------------
// Merge split-K partials: Ob = (sum_ch O) / (sum_ch l), bf16.
// ---------------------------------------------------------------------------
__global__ __launch_bounds__(256) void k_merge(const float* __restrict__ Opart,
                                               const float* __restrict__ Lpart,
                                               ushort_t* __restrict__ Ob) {
    int t = blockIdx.x * 256 + threadIdx.x;
    int e = t * 4;                       // flat over [h][row][c]
    int c = e & (HD - 1);
    int row = (e >> 6) % NTOK;
    int h = e / (NTOK * HD);
    const int ostride = HEADS * NTOK * HD;
    float4 s = {0.f, 0.f, 0.f, 0.f};
    float l = 0.f;
    #pragma unroll
    for (int ch = 0; ch < CHUNKS; ch++) {
        float4 v = *(const float4*)&Opart[(size_t)ch * ostride + e];
        s.x += v.x; s.y += v.y; s.z += v.z; s.w += v.w;
        l += Lpart[(size_t)(ch * HEADS + h) * NTOK + row];
    }
    float inv = 1.0f / l;
    ushort4 o = make_ushort4(f2bf(s.x * inv), f2bf(s.y * inv),
                             f2bf(s.z * inv), f2bf(s.w * inv));
    *(ushort4*)&Ob[(size_t)row * DIM + h * HD + c] = o;
}

// ---------------------------------------------------------------------------
// Output projection: 128x128 tile, 2x2 waves of 64x64, stride-40 LDS.
// ---------------------------------------------------------------------------
__global__ __launch_bounds__(256) void k_gemm_proj(
    const ushort_t* __restrict__ Ob, const ushort_t* __restrict__ WTp,
    const float* __restrict__ bp, float* __restrict__ out) {
    __shared__ __align__(16) ushort_t As[128 * 40];
    __shared__ __align__(16) ushort_t Bs[128 * 40];
    int tid = threadIdx.x;
    int wave = tid >> 6, lane = tid & 63, quad = lane >> 4, l16 = lane & 15;
    int wx = wave & 1, wy = wave >> 1;
    int nb = blockIdx.x * 128, mb = blockIdx.y * 128;

    f32x4 zero = {0.f, 0.f, 0.f, 0.f};
    f32x4 acc[4][4];
    #pragma unroll
    for (int i = 0; i < 4; i++)
        #pragma unroll
        for (int j = 0; j < 4; j++) acc[i][j] = zero;

    const ushort_t* Ag = Ob + (size_t)(mb + (tid >> 1)) * DIM + (tid & 1) * 16;
    const ushort_t* Bg = WTp + (size_t)(nb + (tid >> 1)) * DIM + (tid & 1) * 16;
    int sidx = (tid >> 1) * 40 + (tid & 1) * 16;

    for (int k0 = 0; k0 < DIM; k0 += 32) {
        uint4 a0 = *(const uint4*)(Ag + k0);
        uint4 a1 = *(const uint4*)(Ag + k0 + 8);
        uint4 b0 = *(const uint4*)(Bg + k0);
        uint4 b1 = *(const uint4*)(Bg + k0 + 8);
        __syncthreads();
        *(uint4*)&As[sidx] = a0;  *(uint4*)&As[sidx + 8] = a1;
        *(uint4*)&Bs[sidx] = b0;  *(uint4*)&Bs[sidx + 8] = b1;
        __syncthreads();
        bf16x8 af[4], bf[4];
        #pragma unroll
        for (int i = 0; i < 4; i++)
            af[i] = *(const bf16x8*)&As[(wy * 64 + i * 16 + l16) * 40 + quad * 8];
        #pragma unroll
        for (int j = 0; j < 4; j++)
            bf[j] = *(const bf16x8*)&Bs[(wx * 64 + j * 16 + l16) * 40 + quad * 8];
        #pragma unroll
        for (int i = 0; i < 4; i++)
            #pragma unroll
            for (int j = 0; j < 4; j++)
                acc[i][j] = __builtin_amdgcn_mfma_f32_16x16x32_bf16(af[i], bf[j], acc[i][j], 0, 0, 0);
    }

    #pragma unroll
    for (int j = 0; j < 4; j++) {
        int col = nb + wx * 64 + j * 16 + l16;
        float bval = bp[col];
        #pragma unroll
        for (int i = 0; i < 4; i++) {
            #pragma unroll
            for (int r = 0; r < 4; r++) {
                int row = mb + wy * 64 + i * 16 + quad * 4 + r;
                out[(size_t)row * DIM + col] = acc[i][j][r] + bval;
            }
        }
    }
}

// ---------------------------------------------------------------------------
extern "C" void kernel_launch(void* const* d_in, const int* in_sizes, int n_in,
                              void* d_out, int out_size, void* d_ws, size_t ws_size,
                              hipStream_t stream) {
    const float* x   = (const float*)d_in[0];
    const float* Wq  = (const float*)d_in[1];
    const float* bq  = (const float*)d_in[2];
    const float* Wk  = (const float*)d_in[3];
    const float* bk  = (const float*)d_in[4];
    const float* Wv  = (const float*)d_in[5];
    const float* bv  = (const float*)d_in[6];
    const float* Wp  = (const float*)d_in[7];
    const float* bp  = (const float*)d_in[8];
    const float* rph = (const float*)d_in[9];
    const float* rpw = (const float*)d_in[10];
    const float* Aq  = (const float*)d_in[11];
    const float* Bq  = (const float*)d_in[12];
    const float* Ak  = (const float*)d_in[13];
    const float* Bk  = (const float*)d_in[14];
    const float* Av  = (const float*)d_in[15];
    const float* Bv  = (const float*)d_in[16];
    float* out = (float*)d_out;

    char* w = (char*)d_ws;
    size_t off = 0;
    auto carve = [&](size_t bytes) {
        char* p = w + off;
        off += (bytes + 255) & ~(size_t)255;
        return p;
    };
    ushort_t* xb    = (ushort_t*)carve((size_t)NTOK * DIM * 2);
    ushort_t* WT    = (ushort_t*)carve((size_t)4 * DIM * DIM * 2);
    ushort_t* Qb    = (ushort_t*)carve((size_t)HEADS * NTOK * HD * 2);
    ushort_t* Kb    = (ushort_t*)carve((size_t)HEADS * NTOK * HD * 2);
    ushort_t* Vtb   = (ushort_t*)carve((size_t)HEADS * HD * NTOK * 2);
    float*    relH  = (float*)carve((size_t)HEADS * NTOK * GRD * 4);
    float*    relW  = (float*)carve((size_t)HEADS * NTOK * GRD * 4);
    ushort_t* Ob    = (ushort_t*)carve((size_t)NTOK * DIM * 2);
    float*    Opart = (float*)carve((size_t)CHUNKS * HEADS * NTOK * HD * 4);
    float*    Lpart = (float*)carve((size_t)CHUNKS * HEADS * NTOK * 4);
    ushort_t* rphb  = (ushort_t*)carve((size_t)(2 * GRD - 1) * HD * 2);
    ushort_t* rpwb  = (ushort_t*)carve((size_t)(2 * GRD - 1) * HD * 2);

    k_prep<<<dim3(2304), dim3(256), 0, stream>>>(
        x, xb, rph, rpw, rphb, rpwb,
        Wq, Wk, Wv, Wp, Aq, Bq, Ak, Bk, Av, Bv, WT);
    k_gemm_qkv<<<dim3(18, 18), dim3(256), 0, stream>>>(
        xb, WT, bq, bk, bv, Qb, Kb, Vtb);
    k_relmm<<<dim3(288), dim3(256), 0, stream>>>(
        Qb, rphb, rpwb, relH, relW);
    k_attn<<<dim3(HEADS * CHUNKS, NTOK / 128), dim3(256), 0, stream>>>(
        Qb, Kb, Vtb, relH, relW, Opart, Lpart);
    k_merge<<<dim3(HEADS * NTOK * HD / (256 * 4)), dim3(256), 0, stream>>>(
        Opart, Lpart, Ob);
    k_gemm_proj<<<dim3(6, 18), dim3(256), 0, stream>>>(
        Ob, WT + (size_t)3 * DIM * DIM, bp, out);
}

// Round 9
// 217.469 us; speedup vs baseline: 1.0207x; 1.0207x over previous
//
#include <hip/hip_runtime.h>

// ---------------------------------------------------------------------------
// LoRA_Attention: fold LoRA into weights; bf16 MFMA GEMMs; split-K flash
// attention (S^T core, registerized relW, 38.4 KB LDS -> 4 blocks/CU by LDS,
// NO launch_bounds min-waves clause — (256,4) forced VGPR 64 + spills in R8);
// BK=32 DMA QKV GEMM; 216-block DMA proj GEMM; fused convert+fold.
// exp2 softmax, no-max (scores bounded). XCD-swizzled attn grid.
// ---------------------------------------------------------------------------

#define DIM   768
#define HEADS 12
#define HD    64
#define NTOK  2304
#define RANK  8
#define GRD   48
#define CHUNKS 4
#define LOG2E 1.44269504088896f

typedef __attribute__((ext_vector_type(8))) short bf16x8;
typedef __attribute__((ext_vector_type(4))) float f32x4;
typedef unsigned short ushort_t;

__device__ __forceinline__ unsigned short f2bf(float x) {
    union { float f; unsigned u; } v; v.f = x;
    unsigned r = v.u + 0x7fffu + ((v.u >> 16) & 1u);
    return (unsigned short)(r >> 16);
}
__device__ __forceinline__ float bf2f(unsigned short h) {
    return __uint_as_float(((unsigned)h) << 16);
}
__device__ __forceinline__ void gload_lds16(const ushort_t* g, ushort_t* l) {
    __builtin_amdgcn_global_load_lds(
        (const __attribute__((address_space(1))) unsigned int*)g,
        (__attribute__((address_space(3))) unsigned int*)l, 16, 0, 0);
}

// ---------------------------------------------------------------------------
// k_prep: fold LoRA into transposed weights (all 2304 blocks) + convert
// x / rel tables to bf16 (blocks < 1740). Independent tasks, one launch.
// ---------------------------------------------------------------------------
__global__ __launch_bounds__(256) void k_prep(
    const float* __restrict__ x, ushort_t* __restrict__ xb,
    const float* __restrict__ rph, const float* __restrict__ rpw,
    ushort_t* __restrict__ rphb, ushort_t* __restrict__ rpwb,
    const float* __restrict__ Wq, const float* __restrict__ Wk,
    const float* __restrict__ Wv, const float* __restrict__ Wp,
    const float* __restrict__ Aq, const float* __restrict__ Bq,
    const float* __restrict__ Ak, const float* __restrict__ Bk,
    const float* __restrict__ Av, const float* __restrict__ Bv,
    ushort_t* __restrict__ WT) {
    int bid = blockIdx.x, tid = threadIdx.x;

    if (bid < 1740) {
        if (bid < 1728) {
            int idx = (bid * 256 + tid) * 4;
            float4 v = *(const float4*)(x + idx);
            ushort4 o = make_ushort4(f2bf(v.x), f2bf(v.y), f2bf(v.z), f2bf(v.w));
            *(ushort4*)(xb + idx) = o;
        } else {
            int e = ((bid - 1728) * 256 + tid) * 4;
            const int TSZ = (2 * GRD - 1) * HD;   // 6080
            if (e < TSZ) {
                float4 v = *(const float4*)(rph + e);
                ushort4 o = make_ushort4(f2bf(v.x), f2bf(v.y), f2bf(v.z), f2bf(v.w));
                *(ushort4*)(rphb + e) = o;
            } else if (e < 2 * TSZ) {
                float4 v = *(const float4*)(rpw + e - TSZ);
                ushort4 o = make_ushort4(f2bf(v.x), f2bf(v.y), f2bf(v.z), f2bf(v.w));
                *(ushort4*)(rpwb + e - TSZ) = o;
            }
        }
    }

    int kb = (bid % 24) * 32;
    int nb = (bid / 24) * 32;
    int sel = nb / DIM, nmod = nb % DIM;
    const float* W = (sel == 0) ? Wq : (sel == 1) ? Wk : (sel == 2) ? Wv : Wp;
    const float* A = (sel == 0) ? Aq : (sel == 1) ? Ak : Av;
    const float* B = (sel == 0) ? Bq : (sel == 1) ? Bk : Bv;
    __shared__ float T[32][33];
    for (int i = tid; i < 1024; i += 256) {
        int kl = i >> 5, nl = i & 31;
        float v = W[(kb + kl) * DIM + nmod + nl];
        if (sel < 3) {
            #pragma unroll
            for (int r = 0; r < RANK; r++)
                v += A[(kb + kl) * RANK + r] * B[r * DIM + nmod + nl];
        }
        T[kl][nl] = v;
    }
    __syncthreads();
    for (int i = tid; i < 1024; i += 256) {
        int nl = i >> 5, kl = i & 31;
        WT[(size_t)(nb + nl) * DIM + kb + kl] = f2bf(T[kl][nl]);
    }
}

// ---------------------------------------------------------------------------
// QKV GEMM: 128x128 tile, BK=32 (proven), global_load_lds width-16 DMA.
// ---------------------------------------------------------------------------
__global__ __launch_bounds__(256) void k_gemm_qkv(
    const ushort_t* __restrict__ xb, const ushort_t* __restrict__ WT,
    const float* __restrict__ bq, const float* __restrict__ bk,
    const float* __restrict__ bv,
    ushort_t* __restrict__ Qb, ushort_t* __restrict__ Kb,
    ushort_t* __restrict__ Vtb) {
    __shared__ __align__(16) ushort_t As[128 * 32];
    __shared__ __align__(16) ushort_t Bs[128 * 32];
    int tid = threadIdx.x;
    int wave = tid >> 6, lane = tid & 63, quad = lane >> 4, l16 = lane & 15;
    int wx = wave & 1, wy = wave >> 1;
    int nb = blockIdx.x * 128, mb = blockIdx.y * 128;

    f32x4 zero = {0.f, 0.f, 0.f, 0.f};
    f32x4 acc[4][4];
    #pragma unroll
    for (int i = 0; i < 4; i++)
        #pragma unroll
        for (int j = 0; j < 4; j++) acc[i][j] = zero;

    int rl = lane >> 2;            // 0..15
    int cl = (lane & 3) * 8;       // element col within 32
    const ushort_t* gA = xb + (size_t)(mb + wave * 32 + rl) * DIM + cl;
    const ushort_t* gB = WT + (size_t)(nb + wave * 32 + rl) * DIM + cl;
    ushort_t* lA = &As[(wave * 32) * 32];   // HW adds lane*16B
    ushort_t* lB = &Bs[(wave * 32) * 32];

    for (int k0 = 0; k0 < DIM; k0 += 32) {
        __syncthreads();
        gload_lds16(gA + k0,            lA);
        gload_lds16(gA + k0 + 16 * DIM, lA + 16 * 32);
        gload_lds16(gB + k0,            lB);
        gload_lds16(gB + k0 + 16 * DIM, lB + 16 * 32);
        __syncthreads();
        bf16x8 af[4], bf[4];
        #pragma unroll
        for (int i = 0; i < 4; i++)
            af[i] = *(const bf16x8*)&As[(wy * 64 + i * 16 + l16) * 32 + quad * 8];
        #pragma unroll
        for (int j = 0; j < 4; j++)
            bf[j] = *(const bf16x8*)&Bs[(wx * 64 + j * 16 + l16) * 32 + quad * 8];
        #pragma unroll
        for (int i = 0; i < 4; i++)
            #pragma unroll
            for (int j = 0; j < 4; j++)
                acc[i][j] = __builtin_amdgcn_mfma_f32_16x16x32_bf16(af[i], bf[j], acc[i][j], 0, 0, 0);
    }

    #pragma unroll
    for (int j = 0; j < 4; j++) {
        int col = nb + wx * 64 + j * 16 + l16;
        int sel = col / DIM, rem = col % DIM;
        int hh = rem >> 6, cc = rem & 63;
        const float* bias = (sel == 0) ? bq : (sel == 1) ? bk : bv;
        float bval = bias[rem];
        #pragma unroll
        for (int i = 0; i < 4; i++) {
            #pragma unroll
            for (int r = 0; r < 4; r++) {
                int row = mb + wy * 64 + i * 16 + quad * 4 + r;
                unsigned short o = f2bf(acc[i][j][r] + bval);
                if (sel == 0)      Qb[(size_t)(hh * NTOK + row) * HD + cc] = o;
                else if (sel == 1) Kb[(size_t)(hh * NTOK + row) * HD + cc] = o;
                else               Vtb[(size_t)(hh * HD + cc) * NTOK + row] = o;
            }
        }
    }
}

// ---------------------------------------------------------------------------
// Rel-pos bias via MFMA (outputs pre-scaled by log2 e).
// ---------------------------------------------------------------------------
__global__ __launch_bounds__(256) void k_relmm(
    const ushort_t* __restrict__ Qb, const ushort_t* __restrict__ rphb,
    const ushort_t* __restrict__ rpwb, float* __restrict__ relH,
    float* __restrict__ relW) {
    int id = blockIdx.x * 4 + (threadIdx.x >> 6);
    int lane = threadIdx.x & 63, quad = lane >> 4, l16 = lane & 15;
    bool isW = id >= 576;
    int t = isW ? id - 576 : id;
    int h = t / GRD, g = t % GRD;
    const ushort_t* tab = isW ? rpwb : rphb;
    float* outp = isW ? relW : relH;

    f32x4 zero = {0.f, 0.f, 0.f, 0.f};
    f32x4 acc[3][3];
    #pragma unroll
    for (int i = 0; i < 3; i++)
        #pragma unroll
        for (int j = 0; j < 3; j++) acc[i][j] = zero;

    bf16x8 bfr[3][2];
    #pragma unroll
    for (int ct = 0; ct < 3; ct++) {
        int trow = g + 47 - (ct * 16 + l16);
        bfr[ct][0] = *(const bf16x8*)&tab[(size_t)trow * HD + quad * 8];
        bfr[ct][1] = *(const bf16x8*)&tab[(size_t)trow * HD + 32 + quad * 8];
    }
    #pragma unroll
    for (int ms = 0; ms < 3; ms++) {
        int m = ms * 16 + l16;
        int n = isW ? m * GRD + g : g * GRD + m;
        bf16x8 a0 = *(const bf16x8*)&Qb[(size_t)(h * NTOK + n) * HD + quad * 8];
        bf16x8 a1 = *(const bf16x8*)&Qb[(size_t)(h * NTOK + n) * HD + 32 + quad * 8];
        #pragma unroll
        for (int ct = 0; ct < 3; ct++) {
            acc[ms][ct] = __builtin_amdgcn_mfma_f32_16x16x32_bf16(a0, bfr[ct][0], acc[ms][ct], 0, 0, 0);
            acc[ms][ct] = __builtin_amdgcn_mfma_f32_16x16x32_bf16(a1, bfr[ct][1], acc[ms][ct], 0, 0, 0);
        }
    }
    #pragma unroll
    for (int ms = 0; ms < 3; ms++) {
        #pragma unroll
        for (int ct = 0; ct < 3; ct++) {
            #pragma unroll
            for (int r = 0; r < 4; r++) {
                int m = ms * 16 + quad * 4 + r;
                int n = isW ? m * GRD + g : g * GRD + m;
                int col = ct * 16 + l16;
                outp[(size_t)(h * NTOK + n) * GRD + col] = acc[ms][ct][r] * LOG2E;
            }
        }
    }
}

// ---------------------------------------------------------------------------
// Flash attention, split-K. Block = (128 q-rows, head, chunk of 576 keys).
// Grid x = h*4+chunk (XCD-local K/V sharing). Coalesced uint4 reg-prefetch
// -> stride-68 LDS; S^T compute core; registerized relW (3 uint2/strip).
// 38.4 KB LDS -> 4 blocks/CU via LDS limit; plain launch_bounds(256) so the
// compiler keeps ~108 VGPRs (the (256,4) variant spilled — R8 post-mortem).
// ---------------------------------------------------------------------------
__global__ __launch_bounds__(256) void k_attn(
    const ushort_t* __restrict__ Qb, const ushort_t* __restrict__ Kb,
    const ushort_t* __restrict__ Vtb, const float* __restrict__ relH,
    const float* __restrict__ relW, float* __restrict__ Opart,
    float* __restrict__ Lpart) {
    int h = blockIdx.x >> 2, chunk = blockIdx.x & 3, qt = blockIdx.y;
    int tid = threadIdx.x;
    int wave = tid >> 6, lane = tid & 63, quad = lane >> 4, l16 = lane & 15;
    int qbase = qt * 128;
    int kbase = chunk * 576;

    __shared__ __align__(16) ushort_t Ks[64 * 68];      //  8704 B
    __shared__ __align__(16) ushort_t Vs[64 * 68];      //  8704 B
    __shared__ __align__(16) ushort_t Ps[4][32 * 68];   // 17408 B
    __shared__ __align__(16) ushort_t rhs[128 * 14];    //  3584 B  (38.4 KB)

    // stage rel_h (12 kh of this chunk), bf16
    for (int i = tid; i < 128 * 12; i += 256) {
        int r = i / 12, c = i % 12;
        rhs[r * 14 + c] = f2bf(relH[(size_t)(h * NTOK + qbase + r) * GRD + chunk * 12 + c]);
    }

    // Q B-fragments (wave owns 32 rows = 2 strips)
    bf16x8 qf[2][2];
    #pragma unroll
    for (int s = 0; s < 2; s++) {
        int qrow = qbase + wave * 32 + s * 16 + l16;
        qf[s][0] = *(const bf16x8*)&Qb[(size_t)(h * NTOK + qrow) * HD + quad * 8];
        qf[s][1] = *(const bf16x8*)&Qb[(size_t)(h * NTOK + qrow) * HD + 32 + quad * 8];
    }
    // registerized relW: packed bf16 pairs for kw0 = m3*16 + quad*4
    uint2 rwreg[2][3];
    #pragma unroll
    for (int s = 0; s < 2; s++) {
        int row = qbase + wave * 32 + s * 16 + l16;
        const float* rp = relW + (size_t)(h * NTOK + row) * GRD + quad * 4;
        #pragma unroll
        for (int m3 = 0; m3 < 3; m3++) {
            float4 rw = *(const float4*)(rp + m3 * 16);
            uint2 u;
            u.x = (unsigned)f2bf(rw.x) | ((unsigned)f2bf(rw.y) << 16);
            u.y = (unsigned)f2bf(rw.z) | ((unsigned)f2bf(rw.w) << 16);
            rwreg[s][m3] = u;
        }
    }

    int r0 = tid >> 3, c0 = (tid & 7) * 8;
    const ushort_t* kg0 = Kb + (size_t)(h * NTOK + r0) * HD + c0;
    const ushort_t* kg1 = Kb + (size_t)(h * NTOK + r0 + 32) * HD + c0;
    const ushort_t* vg0 = Vtb + (size_t)(h * HD + r0) * NTOK + c0;
    const ushort_t* vg1 = Vtb + (size_t)(h * HD + r0 + 32) * NTOK + c0;
    int sk0 = r0 * 68 + c0, sk1 = sk0 + 32 * 68;

    float lacc[2] = {0.f, 0.f};
    f32x4 zero = {0.f, 0.f, 0.f, 0.f};
    f32x4 oacc[2][4];
    #pragma unroll
    for (int s = 0; s < 2; s++)
        #pragma unroll
        for (int cs = 0; cs < 4; cs++) oacc[s][cs] = zero;

    const float scale2 = 0.125f * LOG2E;

    uint4 rk0 = *(const uint4*)(kg0 + (size_t)kbase * HD);
    uint4 rk1 = *(const uint4*)(kg1 + (size_t)kbase * HD);
    uint4 rv0 = *(const uint4*)(vg0 + kbase);
    uint4 rv1 = *(const uint4*)(vg1 + kbase);

    for (int kt = 0; kt < 9; kt++) {
        int kb = kbase + kt * 64;
        __syncthreads();                 // all waves done reading prev K/V tile
        *(uint4*)&Ks[sk0] = rk0;  *(uint4*)&Ks[sk1] = rk1;
        *(uint4*)&Vs[sk0] = rv0;  *(uint4*)&Vs[sk1] = rv1;
        __syncthreads();
        if (kt < 8) {                    // issue next tile's loads
            int kbn = kb + 64;
            rk0 = *(const uint4*)(kg0 + (size_t)kbn * HD);
            rk1 = *(const uint4*)(kg1 + (size_t)kbn * HD);
            rv0 = *(const uint4*)(vg0 + kbn);
            rv1 = *(const uint4*)(vg1 + kbn);
        }

        // QK^T (S^T: D[m=key][n=qrow]) + softmax + packed P store
        #pragma unroll
        for (int ks = 0; ks < 4; ks++) {
            bf16x8 kf0 = *(const bf16x8*)&Ks[(ks * 16 + l16) * 68 + quad * 8];
            bf16x8 kf1 = *(const bf16x8*)&Ks[(ks * 16 + l16) * 68 + 32 + quad * 8];
            f32x4 st[2];
            #pragma unroll
            for (int s = 0; s < 2; s++) {
                f32x4 z = zero;
                z = __builtin_amdgcn_mfma_f32_16x16x32_bf16(kf0, qf[s][0], z, 0, 0, 0);
                z = __builtin_amdgcn_mfma_f32_16x16x32_bf16(kf1, qf[s][1], z, 0, 0, 0);
                st[s] = z;
            }
            int kb4 = kb + ks * 16 + quad * 4;
            int khl = kb4 / 48 - chunk * 12;      // uniform per 16-key group
            int m3 = (kt + ks) % 3;               // lane-uniform
            #pragma unroll
            for (int s = 0; s < 2; s++) {
                int row = wave * 32 + s * 16 + l16;
                float rh = bf2f(rhs[row * 14 + khl]);
                uint2 u = (m3 == 0) ? rwreg[s][0] : (m3 == 1) ? rwreg[s][1] : rwreg[s][2];
                float p0 = __builtin_amdgcn_exp2f(st[s][0] * scale2 + rh + __uint_as_float(u.x << 16));
                float p1 = __builtin_amdgcn_exp2f(st[s][1] * scale2 + rh + __uint_as_float(u.x & 0xffff0000u));
                float p2 = __builtin_amdgcn_exp2f(st[s][2] * scale2 + rh + __uint_as_float(u.y << 16));
                float p3 = __builtin_amdgcn_exp2f(st[s][3] * scale2 + rh + __uint_as_float(u.y & 0xffff0000u));
                lacc[s] += (p0 + p1) + (p2 + p3);
                uint2 w;
                w.x = __builtin_amdgcn_perm(__float_as_uint(p1), __float_as_uint(p0), 0x07060302u);
                w.y = __builtin_amdgcn_perm(__float_as_uint(p3), __float_as_uint(p2), 0x07060302u);
                *(uint2*)&Ps[wave][(s * 16 + l16) * 68 + ks * 16 + quad * 4] = w;
            }
        }

        // PV: A[m=qrow][k=key] b128 from own Ps; B[k=key][n=c] b128 from Vs
        bf16x8 vf[4][2];
        #pragma unroll
        for (int cs = 0; cs < 4; cs++) {
            vf[cs][0] = *(const bf16x8*)&Vs[(cs * 16 + l16) * 68 + quad * 8];
            vf[cs][1] = *(const bf16x8*)&Vs[(cs * 16 + l16) * 68 + 32 + quad * 8];
        }
        #pragma unroll
        for (int s = 0; s < 2; s++) {
            bf16x8 pa0 = *(const bf16x8*)&Ps[wave][(s * 16 + l16) * 68 + quad * 8];
            bf16x8 pa1 = *(const bf16x8*)&Ps[wave][(s * 16 + l16) * 68 + 32 + quad * 8];
            #pragma unroll
            for (int cs = 0; cs < 4; cs++) {
                oacc[s][cs] = __builtin_amdgcn_mfma_f32_16x16x32_bf16(pa0, vf[cs][0], oacc[s][cs], 0, 0, 0);
                oacc[s][cs] = __builtin_amdgcn_mfma_f32_16x16x32_bf16(pa1, vf[cs][1], oacc[s][cs], 0, 0, 0);
            }
        }
    }

    // l: reduce over quads (keys split across quads)
    #pragma unroll
    for (int s = 0; s < 2; s++) {
        float l = lacc[s];
        l += __shfl_xor(l, 16);
        l += __shfl_xor(l, 32);
        lacc[s] = l;
    }

    // write partials: Opart [chunk][h][tok][c], Lpart [chunk][h][tok]
    size_t obase = (size_t)(chunk * HEADS + h) * NTOK;
    #pragma unroll
    for (int s = 0; s < 2; s++) {
        #pragma unroll
        for (int cs = 0; cs < 4; cs++) {
            #pragma unroll
            for (int r = 0; r < 4; r++) {
                int row = qbase + wave * 32 + s * 16 + quad * 4 + r;
                Opart[(obase + row) * HD + cs * 16 + l16] = oacc[s][cs][r];
            }
        }
        if (quad == 0)
            Lpart[obase + qbase + wave * 32 + s * 16 + l16] = lacc[s];
    }
}

// ---------------------------------------------------------------------------
// Merge split-K partials: Ob = (sum_ch O) / (sum_ch l), bf16.
// ---------------------------------------------------------------------------
__global__ __launch_bounds__(256) void k_merge(const float* __restrict__ Opart,
                                               const float* __restrict__ Lpart,
                                               ushort_t* __restrict__ Ob) {
    int t = blockIdx.x * 256 + threadIdx.x;
    int e = t * 4;                       // flat over [h][row][c]
    int c = e & (HD - 1);
    int row = (e >> 6) % NTOK;
    int h = e / (NTOK * HD);
    const int ostride = HEADS * NTOK * HD;
    float4 s = {0.f, 0.f, 0.f, 0.f};
    float l = 0.f;
    #pragma unroll
    for (int ch = 0; ch < CHUNKS; ch++) {
        float4 v = *(const float4*)&Opart[(size_t)ch * ostride + e];
        s.x += v.x; s.y += v.y; s.z += v.z; s.w += v.w;
        l += Lpart[(size_t)(ch * HEADS + h) * NTOK + row];
    }
    float inv = 1.0f / l;
    ushort4 o = make_ushort4(f2bf(s.x * inv), f2bf(s.y * inv),
                             f2bf(s.z * inv), f2bf(s.w * inv));
    *(ushort4*)&Ob[(size_t)row * DIM + h * HD + c] = o;
}

// ---------------------------------------------------------------------------
// Output projection: 128(M)x64(N) tiles -> 216 blocks (was 108), BK=32,
// global_load_lds DMA staging, 12 KB LDS. 2x2 waves: wave = 64 rows x 32 cols.
// ---------------------------------------------------------------------------
__global__ __launch_bounds__(256) void k_gemm_proj(
    const ushort_t* __restrict__ Ob, const ushort_t* __restrict__ WTp,
    const float* __restrict__ bp, float* __restrict__ out) {
    __shared__ __align__(16) ushort_t As[128 * 32];   // 8 KB
    __shared__ __align__(16) ushort_t Bs[64 * 32];    // 4 KB
    int tid = threadIdx.x;
    int wave = tid >> 6, lane = tid & 63, quad = lane >> 4, l16 = lane & 15;
    int wx = wave & 1, wy = wave >> 1;
    int nb = blockIdx.x * 64, mb = blockIdx.y * 128;

    f32x4 zero = {0.f, 0.f, 0.f, 0.f};
    f32x4 acc[4][2];
    #pragma unroll
    for (int i = 0; i < 4; i++)
        #pragma unroll
        for (int j = 0; j < 2; j++) acc[i][j] = zero;

    int rl = lane >> 2;            // 0..15
    int cl = (lane & 3) * 8;       // element col within 32
    const ushort_t* gA = Ob + (size_t)(mb + wave * 32 + rl) * DIM + cl;
    const ushort_t* gB = WTp + (size_t)(nb + wave * 16 + rl) * DIM + cl;
    ushort_t* lA = &As[(wave * 32) * 32];
    ushort_t* lB = &Bs[(wave * 16) * 32];

    for (int k0 = 0; k0 < DIM; k0 += 32) {
        __syncthreads();
        gload_lds16(gA + k0,            lA);
        gload_lds16(gA + k0 + 16 * DIM, lA + 16 * 32);
        gload_lds16(gB + k0,            lB);
        __syncthreads();
        bf16x8 af[4], bf[2];
        #pragma unroll
        for (int i = 0; i < 4; i++)
            af[i] = *(const bf16x8*)&As[(wy * 64 + i * 16 + l16) * 32 + quad * 8];
        #pragma unroll
        for (int j = 0; j < 2; j++)
            bf[j] = *(const bf16x8*)&Bs[(wx * 32 + j * 16 + l16) * 32 + quad * 8];
        #pragma unroll
        for (int i = 0; i < 4; i++)
            #pragma unroll
            for (int j = 0; j < 2; j++)
                acc[i][j] = __builtin_amdgcn_mfma_f32_16x16x32_bf16(af[i], bf[j], acc[i][j], 0, 0, 0);
    }

    #pragma unroll
    for (int j = 0; j < 2; j++) {
        int col = nb + wx * 32 + j * 16 + l16;
        float bval = bp[col];
        #pragma unroll
        for (int i = 0; i < 4; i++) {
            #pragma unroll
            for (int r = 0; r < 4; r++) {
                int row = mb + wy * 64 + i * 16 + quad * 4 + r;
                out[(size_t)row * DIM + col] = acc[i][j][r] + bval;
            }
        }
    }
}

// ---------------------------------------------------------------------------
extern "C" void kernel_launch(void* const* d_in, const int* in_sizes, int n_in,
                              void* d_out, int out_size, void* d_ws, size_t ws_size,
                              hipStream_t stream) {
    const float* x   = (const float*)d_in[0];
    const float* Wq  = (const float*)d_in[1];
    const float* bq  = (const float*)d_in[2];
    const float* Wk  = (const float*)d_in[3];
    const float* bk  = (const float*)d_in[4];
    const float* Wv  = (const float*)d_in[5];
    const float* bv  = (const float*)d_in[6];
    const float* Wp  = (const float*)d_in[7];
    const float* bp  = (const float*)d_in[8];
    const float* rph = (const float*)d_in[9];
    const float* rpw = (const float*)d_in[10];
    const float* Aq  = (const float*)d_in[11];
    const float* Bq  = (const float*)d_in[12];
    const float* Ak  = (const float*)d_in[13];
    const float* Bk  = (const float*)d_in[14];
    const float* Av  = (const float*)d_in[15];
    const float* Bv  = (const float*)d_in[16];
    float* out = (float*)d_out;

    char* w = (char*)d_ws;
    size_t off = 0;
    auto carve = [&](size_t bytes) {
        char* p = w + off;
        off += (bytes + 255) & ~(size_t)255;
        return p;
    };
    ushort_t* xb    = (ushort_t*)carve((size_t)NTOK * DIM * 2);
    ushort_t* WT    = (ushort_t*)carve((size_t)4 * DIM * DIM * 2);
    ushort_t* Qb    = (ushort_t*)carve((size_t)HEADS * NTOK * HD * 2);
    ushort_t* Kb    = (ushort_t*)carve((size_t)HEADS * NTOK * HD * 2);
    ushort_t* Vtb   = (ushort_t*)carve((size_t)HEADS * HD * NTOK * 2);
    float*    relH  = (float*)carve((size_t)HEADS * NTOK * GRD * 4);
    float*    relW  = (float*)carve((size_t)HEADS * NTOK * GRD * 4);
    ushort_t* Ob    = (ushort_t*)carve((size_t)NTOK * DIM * 2);
    float*    Opart = (float*)carve((size_t)CHUNKS * HEADS * NTOK * HD * 4);
    float*    Lpart = (float*)carve((size_t)CHUNKS * HEADS * NTOK * 4);
    ushort_t* rphb  = (ushort_t*)carve((size_t)(2 * GRD - 1) * HD * 2);
    ushort_t* rpwb  = (ushort_t*)carve((size_t)(2 * GRD - 1) * HD * 2);

    k_prep<<<dim3(2304), dim3(256), 0, stream>>>(
        x, xb, rph, rpw, rphb, rpwb,
        Wq, Wk, Wv, Wp, Aq, Bq, Ak, Bk, Av, Bv, WT);
    k_gemm_qkv<<<dim3(18, 18), dim3(256), 0, stream>>>(
        xb, WT, bq, bk, bv, Qb, Kb, Vtb);
    k_relmm<<<dim3(288), dim3(256), 0, stream>>>(
        Qb, rphb, rpwb, relH, relW);
    k_attn<<<dim3(HEADS * CHUNKS, NTOK / 128), dim3(256), 0, stream>>>(
        Qb, Kb, Vtb, relH, relW, Opart, Lpart);
    k_merge<<<dim3(HEADS * NTOK * HD / (256 * 4)), dim3(256), 0, stream>>>(
        Opart, Lpart, Ob);
    k_gemm_proj<<<dim3(12, 18), dim3(256), 0, stream>>>(
        Ob, WT + (size_t)3 * DIM * DIM, bp, out);
}

// Round 10
// 200.871 us; speedup vs baseline: 1.1050x; 1.0826x over previous
//
#include <hip/hip_runtime.h>

// ---------------------------------------------------------------------------
// LoRA_Attention: fold LoRA into weights; bf16 MFMA GEMMs; split-K flash
// attention (R6 core: LDS rws, 51.7 KB LDS, ~108 VGPR, zero spill — the
// registerized-relW variants spilled, R8/R9 post-mortems); 128x64 QKV GEMM
// (648 blocks, kills the 324-block CU-packing tail); fused convert+fold.
// exp2 softmax, no-max (scores bounded). XCD-swizzled attn grid.
// ---------------------------------------------------------------------------

#define DIM   768
#define HEADS 12
#define HD    64
#define NTOK  2304
#define RANK  8
#define GRD   48
#define CHUNKS 4
#define LOG2E 1.44269504088896f

typedef __attribute__((ext_vector_type(8))) short bf16x8;
typedef __attribute__((ext_vector_type(4))) float f32x4;
typedef unsigned short ushort_t;

__device__ __forceinline__ unsigned short f2bf(float x) {
    union { float f; unsigned u; } v; v.f = x;
    unsigned r = v.u + 0x7fffu + ((v.u >> 16) & 1u);
    return (unsigned short)(r >> 16);
}
__device__ __forceinline__ float bf2f(unsigned short h) {
    return __uint_as_float(((unsigned)h) << 16);
}
__device__ __forceinline__ void gload_lds16(const ushort_t* g, ushort_t* l) {
    __builtin_amdgcn_global_load_lds(
        (const __attribute__((address_space(1))) unsigned int*)g,
        (__attribute__((address_space(3))) unsigned int*)l, 16, 0, 0);
}

// ---------------------------------------------------------------------------
// k_prep: fold LoRA into transposed weights (all 2304 blocks) + convert
// x / rel tables to bf16 (blocks < 1740). Independent tasks, one launch.
// ---------------------------------------------------------------------------
__global__ __launch_bounds__(256) void k_prep(
    const float* __restrict__ x, ushort_t* __restrict__ xb,
    const float* __restrict__ rph, const float* __restrict__ rpw,
    ushort_t* __restrict__ rphb, ushort_t* __restrict__ rpwb,
    const float* __restrict__ Wq, const float* __restrict__ Wk,
    const float* __restrict__ Wv, const float* __restrict__ Wp,
    const float* __restrict__ Aq, const float* __restrict__ Bq,
    const float* __restrict__ Ak, const float* __restrict__ Bk,
    const float* __restrict__ Av, const float* __restrict__ Bv,
    ushort_t* __restrict__ WT) {
    int bid = blockIdx.x, tid = threadIdx.x;

    if (bid < 1740) {
        if (bid < 1728) {
            int idx = (bid * 256 + tid) * 4;
            float4 v = *(const float4*)(x + idx);
            ushort4 o = make_ushort4(f2bf(v.x), f2bf(v.y), f2bf(v.z), f2bf(v.w));
            *(ushort4*)(xb + idx) = o;
        } else {
            int e = ((bid - 1728) * 256 + tid) * 4;
            const int TSZ = (2 * GRD - 1) * HD;   // 6080
            if (e < TSZ) {
                float4 v = *(const float4*)(rph + e);
                ushort4 o = make_ushort4(f2bf(v.x), f2bf(v.y), f2bf(v.z), f2bf(v.w));
                *(ushort4*)(rphb + e) = o;
            } else if (e < 2 * TSZ) {
                float4 v = *(const float4*)(rpw + e - TSZ);
                ushort4 o = make_ushort4(f2bf(v.x), f2bf(v.y), f2bf(v.z), f2bf(v.w));
                *(ushort4*)(rpwb + e - TSZ) = o;
            }
        }
    }

    int kb = (bid % 24) * 32;
    int nb = (bid / 24) * 32;
    int sel = nb / DIM, nmod = nb % DIM;
    const float* W = (sel == 0) ? Wq : (sel == 1) ? Wk : (sel == 2) ? Wv : Wp;
    const float* A = (sel == 0) ? Aq : (sel == 1) ? Ak : Av;
    const float* B = (sel == 0) ? Bq : (sel == 1) ? Bk : Bv;
    __shared__ float T[32][33];
    for (int i = tid; i < 1024; i += 256) {
        int kl = i >> 5, nl = i & 31;
        float v = W[(kb + kl) * DIM + nmod + nl];
        if (sel < 3) {
            #pragma unroll
            for (int r = 0; r < RANK; r++)
                v += A[(kb + kl) * RANK + r] * B[r * DIM + nmod + nl];
        }
        T[kl][nl] = v;
    }
    __syncthreads();
    for (int i = tid; i < 1024; i += 256) {
        int nl = i >> 5, kl = i & 31;
        WT[(size_t)(nb + nl) * DIM + kb + kl] = f2bf(T[kl][nl]);
    }
}

// ---------------------------------------------------------------------------
// QKV GEMM: 128(M)x64(N) tiles -> 648 blocks (~2.5/CU, no packing tail),
// BK=32, global_load_lds DMA, 12 KB LDS. Waves 2x2: wave = 64 rows x 32 cols.
// ---------------------------------------------------------------------------
__global__ __launch_bounds__(256) void k_gemm_qkv(
    const ushort_t* __restrict__ xb, const ushort_t* __restrict__ WT,
    const float* __restrict__ bq, const float* __restrict__ bk,
    const float* __restrict__ bv,
    ushort_t* __restrict__ Qb, ushort_t* __restrict__ Kb,
    ushort_t* __restrict__ Vtb) {
    __shared__ __align__(16) ushort_t As[128 * 32];   // 8 KB
    __shared__ __align__(16) ushort_t Bs[64 * 32];    // 4 KB
    int tid = threadIdx.x;
    int wave = tid >> 6, lane = tid & 63, quad = lane >> 4, l16 = lane & 15;
    int wx = wave & 1, wy = wave >> 1;
    int nb = blockIdx.x * 64, mb = blockIdx.y * 128;

    f32x4 zero = {0.f, 0.f, 0.f, 0.f};
    f32x4 acc[4][2];
    #pragma unroll
    for (int i = 0; i < 4; i++)
        #pragma unroll
        for (int j = 0; j < 2; j++) acc[i][j] = zero;

    int rl = lane >> 2;            // 0..15
    int cl = (lane & 3) * 8;       // element col within 32
    const ushort_t* gA = xb + (size_t)(mb + wave * 32 + rl) * DIM + cl;
    const ushort_t* gB = WT + (size_t)(nb + wave * 16 + rl) * DIM + cl;
    ushort_t* lA = &As[(wave * 32) * 32];
    ushort_t* lB = &Bs[(wave * 16) * 32];

    for (int k0 = 0; k0 < DIM; k0 += 32) {
        __syncthreads();
        gload_lds16(gA + k0,            lA);
        gload_lds16(gA + k0 + 16 * DIM, lA + 16 * 32);
        gload_lds16(gB + k0,            lB);
        __syncthreads();
        bf16x8 af[4], bf[2];
        #pragma unroll
        for (int i = 0; i < 4; i++)
            af[i] = *(const bf16x8*)&As[(wy * 64 + i * 16 + l16) * 32 + quad * 8];
        #pragma unroll
        for (int j = 0; j < 2; j++)
            bf[j] = *(const bf16x8*)&Bs[(wx * 32 + j * 16 + l16) * 32 + quad * 8];
        #pragma unroll
        for (int i = 0; i < 4; i++)
            #pragma unroll
            for (int j = 0; j < 2; j++)
                acc[i][j] = __builtin_amdgcn_mfma_f32_16x16x32_bf16(af[i], bf[j], acc[i][j], 0, 0, 0);
    }

    #pragma unroll
    for (int j = 0; j < 2; j++) {
        int col = nb + wx * 32 + j * 16 + l16;
        int sel = col / DIM, rem = col % DIM;
        int hh = rem >> 6, cc = rem & 63;
        const float* bias = (sel == 0) ? bq : (sel == 1) ? bk : bv;
        float bval = bias[rem];
        #pragma unroll
        for (int i = 0; i < 4; i++) {
            #pragma unroll
            for (int r = 0; r < 4; r++) {
                int row = mb + wy * 64 + i * 16 + quad * 4 + r;
                unsigned short o = f2bf(acc[i][j][r] + bval);
                if (sel == 0)      Qb[(size_t)(hh * NTOK + row) * HD + cc] = o;
                else if (sel == 1) Kb[(size_t)(hh * NTOK + row) * HD + cc] = o;
                else               Vtb[(size_t)(hh * HD + cc) * NTOK + row] = o;
            }
        }
    }
}

// ---------------------------------------------------------------------------
// Rel-pos bias via MFMA (outputs pre-scaled by log2 e).
// ---------------------------------------------------------------------------
__global__ __launch_bounds__(256) void k_relmm(
    const ushort_t* __restrict__ Qb, const ushort_t* __restrict__ rphb,
    const ushort_t* __restrict__ rpwb, float* __restrict__ relH,
    float* __restrict__ relW) {
    int id = blockIdx.x * 4 + (threadIdx.x >> 6);
    int lane = threadIdx.x & 63, quad = lane >> 4, l16 = lane & 15;
    bool isW = id >= 576;
    int t = isW ? id - 576 : id;
    int h = t / GRD, g = t % GRD;
    const ushort_t* tab = isW ? rpwb : rphb;
    float* outp = isW ? relW : relH;

    f32x4 zero = {0.f, 0.f, 0.f, 0.f};
    f32x4 acc[3][3];
    #pragma unroll
    for (int i = 0; i < 3; i++)
        #pragma unroll
        for (int j = 0; j < 3; j++) acc[i][j] = zero;

    bf16x8 bfr[3][2];
    #pragma unroll
    for (int ct = 0; ct < 3; ct++) {
        int trow = g + 47 - (ct * 16 + l16);
        bfr[ct][0] = *(const bf16x8*)&tab[(size_t)trow * HD + quad * 8];
        bfr[ct][1] = *(const bf16x8*)&tab[(size_t)trow * HD + 32 + quad * 8];
    }
    #pragma unroll
    for (int ms = 0; ms < 3; ms++) {
        int m = ms * 16 + l16;
        int n = isW ? m * GRD + g : g * GRD + m;
        bf16x8 a0 = *(const bf16x8*)&Qb[(size_t)(h * NTOK + n) * HD + quad * 8];
        bf16x8 a1 = *(const bf16x8*)&Qb[(size_t)(h * NTOK + n) * HD + 32 + quad * 8];
        #pragma unroll
        for (int ct = 0; ct < 3; ct++) {
            acc[ms][ct] = __builtin_amdgcn_mfma_f32_16x16x32_bf16(a0, bfr[ct][0], acc[ms][ct], 0, 0, 0);
            acc[ms][ct] = __builtin_amdgcn_mfma_f32_16x16x32_bf16(a1, bfr[ct][1], acc[ms][ct], 0, 0, 0);
        }
    }
    #pragma unroll
    for (int ms = 0; ms < 3; ms++) {
        #pragma unroll
        for (int ct = 0; ct < 3; ct++) {
            #pragma unroll
            for (int r = 0; r < 4; r++) {
                int m = ms * 16 + quad * 4 + r;
                int n = isW ? m * GRD + g : g * GRD + m;
                int col = ct * 16 + l16;
                outp[(size_t)(h * NTOK + n) * GRD + col] = acc[ms][ct][r] * LOG2E;
            }
        }
    }
}

// ---------------------------------------------------------------------------
// Flash attention, split-K — exact R6 core (proven 54.8 us, no spill).
// Block = (128 q-rows, head, chunk of 576 keys). Grid x = h*4+chunk
// (XCD-local K/V sharing). Coalesced uint4 reg-prefetch -> stride-68 LDS;
// S^T compute; rws/rhs staged bf16 in LDS (registerized relW spills — R8/R9).
// ---------------------------------------------------------------------------
__global__ __launch_bounds__(256) void k_attn(
    const ushort_t* __restrict__ Qb, const ushort_t* __restrict__ Kb,
    const ushort_t* __restrict__ Vtb, const float* __restrict__ relH,
    const float* __restrict__ relW, float* __restrict__ Opart,
    float* __restrict__ Lpart) {
    int h = blockIdx.x >> 2, chunk = blockIdx.x & 3, qt = blockIdx.y;
    int tid = threadIdx.x;
    int wave = tid >> 6, lane = tid & 63, quad = lane >> 4, l16 = lane & 15;
    int qbase = qt * 128;
    int kbase = chunk * 576;

    __shared__ __align__(16) ushort_t Ks[64 * 68];
    __shared__ __align__(16) ushort_t Vs[64 * 68];
    __shared__ __align__(16) ushort_t Ps[4][32 * 68];
    __shared__ __align__(16) ushort_t rws[128 * 52];
    __shared__ __align__(16) ushort_t rhs[128 * 14];

    for (int i = tid; i < 128 * 48; i += 256) {
        int r = i / 48, c = i % 48;
        rws[r * 52 + c] = f2bf(relW[(size_t)(h * NTOK + qbase + r) * GRD + c]);
    }
    for (int i = tid; i < 128 * 12; i += 256) {
        int r = i / 12, c = i % 12;
        rhs[r * 14 + c] = f2bf(relH[(size_t)(h * NTOK + qbase + r) * GRD + chunk * 12 + c]);
    }

    bf16x8 qf[2][2];
    #pragma unroll
    for (int s = 0; s < 2; s++) {
        int qrow = qbase + wave * 32 + s * 16 + l16;
        qf[s][0] = *(const bf16x8*)&Qb[(size_t)(h * NTOK + qrow) * HD + quad * 8];
        qf[s][1] = *(const bf16x8*)&Qb[(size_t)(h * NTOK + qrow) * HD + 32 + quad * 8];
    }

    int r0 = tid >> 3, c0 = (tid & 7) * 8;
    const ushort_t* kg0 = Kb + (size_t)(h * NTOK + r0) * HD + c0;
    const ushort_t* kg1 = Kb + (size_t)(h * NTOK + r0 + 32) * HD + c0;
    const ushort_t* vg0 = Vtb + (size_t)(h * HD + r0) * NTOK + c0;
    const ushort_t* vg1 = Vtb + (size_t)(h * HD + r0 + 32) * NTOK + c0;
    int sk0 = r0 * 68 + c0, sk1 = sk0 + 32 * 68;

    float lacc[2] = {0.f, 0.f};
    f32x4 zero = {0.f, 0.f, 0.f, 0.f};
    f32x4 oacc[2][4];
    #pragma unroll
    for (int s = 0; s < 2; s++)
        #pragma unroll
        for (int cs = 0; cs < 4; cs++) oacc[s][cs] = zero;

    const float scale2 = 0.125f * LOG2E;

    uint4 rk0 = *(const uint4*)(kg0 + (size_t)kbase * HD);
    uint4 rk1 = *(const uint4*)(kg1 + (size_t)kbase * HD);
    uint4 rv0 = *(const uint4*)(vg0 + kbase);
    uint4 rv1 = *(const uint4*)(vg1 + kbase);

    for (int kt = 0; kt < 9; kt++) {
        int kb = kbase + kt * 64;
        __syncthreads();
        *(uint4*)&Ks[sk0] = rk0;  *(uint4*)&Ks[sk1] = rk1;
        *(uint4*)&Vs[sk0] = rv0;  *(uint4*)&Vs[sk1] = rv1;
        __syncthreads();
        if (kt < 8) {
            int kbn = kb + 64;
            rk0 = *(const uint4*)(kg0 + (size_t)kbn * HD);
            rk1 = *(const uint4*)(kg1 + (size_t)kbn * HD);
            rv0 = *(const uint4*)(vg0 + kbn);
            rv1 = *(const uint4*)(vg1 + kbn);
        }

        #pragma unroll
        for (int ks = 0; ks < 4; ks++) {
            bf16x8 kf0 = *(const bf16x8*)&Ks[(ks * 16 + l16) * 68 + quad * 8];
            bf16x8 kf1 = *(const bf16x8*)&Ks[(ks * 16 + l16) * 68 + 32 + quad * 8];
            f32x4 st[2];
            #pragma unroll
            for (int s = 0; s < 2; s++) {
                f32x4 z = zero;
                z = __builtin_amdgcn_mfma_f32_16x16x32_bf16(kf0, qf[s][0], z, 0, 0, 0);
                z = __builtin_amdgcn_mfma_f32_16x16x32_bf16(kf1, qf[s][1], z, 0, 0, 0);
                st[s] = z;
            }
            int kb4 = kb + ks * 16 + quad * 4;
            int kh = kb4 / 48;
            int khl = kh - chunk * 12;
            int kw0 = kb4 - kh * 48;
            #pragma unroll
            for (int s = 0; s < 2; s++) {
                int row = wave * 32 + s * 16 + l16;
                float rh = bf2f(rhs[row * 14 + khl]);
                uint2 u = *(const uint2*)&rws[row * 52 + kw0];
                float p0 = __builtin_amdgcn_exp2f(st[s][0] * scale2 + rh + __uint_as_float(u.x << 16));
                float p1 = __builtin_amdgcn_exp2f(st[s][1] * scale2 + rh + __uint_as_float(u.x & 0xffff0000u));
                float p2 = __builtin_amdgcn_exp2f(st[s][2] * scale2 + rh + __uint_as_float(u.y << 16));
                float p3 = __builtin_amdgcn_exp2f(st[s][3] * scale2 + rh + __uint_as_float(u.y & 0xffff0000u));
                lacc[s] += (p0 + p1) + (p2 + p3);
                uint2 w;
                w.x = __builtin_amdgcn_perm(__float_as_uint(p1), __float_as_uint(p0), 0x07060302u);
                w.y = __builtin_amdgcn_perm(__float_as_uint(p3), __float_as_uint(p2), 0x07060302u);
                *(uint2*)&Ps[wave][(s * 16 + l16) * 68 + ks * 16 + quad * 4] = w;
            }
        }

        bf16x8 vf[4][2];
        #pragma unroll
        for (int cs = 0; cs < 4; cs++) {
            vf[cs][0] = *(const bf16x8*)&Vs[(cs * 16 + l16) * 68 + quad * 8];
            vf[cs][1] = *(const bf16x8*)&Vs[(cs * 16 + l16) * 68 + 32 + quad * 8];
        }
        #pragma unroll
        for (int s = 0; s < 2; s++) {
            bf16x8 pa0 = *(const bf16x8*)&Ps[wave][(s * 16 + l16) * 68 + quad * 8];
            bf16x8 pa1 = *(const bf16x8*)&Ps[wave][(s * 16 + l16) * 68 + 32 + quad * 8];
            #pragma unroll
            for (int cs = 0; cs < 4; cs++) {
                oacc[s][cs] = __builtin_amdgcn_mfma_f32_16x16x32_bf16(pa0, vf[cs][0], oacc[s][cs], 0, 0, 0);
                oacc[s][cs] = __builtin_amdgcn_mfma_f32_16x16x32_bf16(pa1, vf[cs][1], oacc[s][cs], 0, 0, 0);
            }
        }
    }

    #pragma unroll
    for (int s = 0; s < 2; s++) {
        float l = lacc[s];
        l += __shfl_xor(l, 16);
        l += __shfl_xor(l, 32);
        lacc[s] = l;
    }

    size_t obase = (size_t)(chunk * HEADS + h) * NTOK;
    #pragma unroll
    for (int s = 0; s < 2; s++) {
        #pragma unroll
        for (int cs = 0; cs < 4; cs++) {
            #pragma unroll
            for (int r = 0; r < 4; r++) {
                int row = qbase + wave * 32 + s * 16 + quad * 4 + r;
                Opart[(obase + row) * HD + cs * 16 + l16] = oacc[s][cs][r];
            }
        }
        if (quad == 0)
            Lpart[obase + qbase + wave * 32 + s * 16 + l16] = lacc[s];
    }
}

// ---------------------------------------------------------------------------
// Merge split-K partials: Ob = (sum_ch O) / (sum_ch l), bf16.
// ---------------------------------------------------------------------------
__global__ __launch_bounds__(256) void k_merge(const float* __restrict__ Opart,
                                               const float* __restrict__ Lpart,
                                               ushort_t* __restrict__ Ob) {
    int t = blockIdx.x * 256 + threadIdx.x;
    int e = t * 4;
    int c = e & (HD - 1);
    int row = (e >> 6) % NTOK;
    int h = e / (NTOK * HD);
    const int ostride = HEADS * NTOK * HD;
    float4 s = {0.f, 0.f, 0.f, 0.f};
    float l = 0.f;
    #pragma unroll
    for (int ch = 0; ch < CHUNKS; ch++) {
        float4 v = *(const float4*)&Opart[(size_t)ch * ostride + e];
        s.x += v.x; s.y += v.y; s.z += v.z; s.w += v.w;
        l += Lpart[(size_t)(ch * HEADS + h) * NTOK + row];
    }
    float inv = 1.0f / l;
    ushort4 o = make_ushort4(f2bf(s.x * inv), f2bf(s.y * inv),
                             f2bf(s.z * inv), f2bf(s.w * inv));
    *(ushort4*)&Ob[(size_t)row * DIM + h * HD + c] = o;
}

// ---------------------------------------------------------------------------
// Output projection: 128(M)x64(N) tiles -> 216 blocks, BK=32,
// global_load_lds DMA staging, 12 KB LDS. 2x2 waves: wave = 64 rows x 32 cols.
// ---------------------------------------------------------------------------
__global__ __launch_bounds__(256) void k_gemm_proj(
    const ushort_t* __restrict__ Ob, const ushort_t* __restrict__ WTp,
    const float* __restrict__ bp, float* __restrict__ out) {
    __shared__ __align__(16) ushort_t As[128 * 32];   // 8 KB
    __shared__ __align__(16) ushort_t Bs[64 * 32];    // 4 KB
    int tid = threadIdx.x;
    int wave = tid >> 6, lane = tid & 63, quad = lane >> 4, l16 = lane & 15;
    int wx = wave & 1, wy = wave >> 1;
    int nb = blockIdx.x * 64, mb = blockIdx.y * 128;

    f32x4 zero = {0.f, 0.f, 0.f, 0.f};
    f32x4 acc[4][2];
    #pragma unroll
    for (int i = 0; i < 4; i++)
        #pragma unroll
        for (int j = 0; j < 2; j++) acc[i][j] = zero;

    int rl = lane >> 2;
    int cl = (lane & 3) * 8;
    const ushort_t* gA = Ob + (size_t)(mb + wave * 32 + rl) * DIM + cl;
    const ushort_t* gB = WTp + (size_t)(nb + wave * 16 + rl) * DIM + cl;
    ushort_t* lA = &As[(wave * 32) * 32];
    ushort_t* lB = &Bs[(wave * 16) * 32];

    for (int k0 = 0; k0 < DIM; k0 += 32) {
        __syncthreads();
        gload_lds16(gA + k0,            lA);
        gload_lds16(gA + k0 + 16 * DIM, lA + 16 * 32);
        gload_lds16(gB + k0,            lB);
        __syncthreads();
        bf16x8 af[4], bf[2];
        #pragma unroll
        for (int i = 0; i < 4; i++)
            af[i] = *(const bf16x8*)&As[(wy * 64 + i * 16 + l16) * 32 + quad * 8];
        #pragma unroll
        for (int j = 0; j < 2; j++)
            bf[j] = *(const bf16x8*)&Bs[(wx * 32 + j * 16 + l16) * 32 + quad * 8];
        #pragma unroll
        for (int i = 0; i < 4; i++)
            #pragma unroll
            for (int j = 0; j < 2; j++)
                acc[i][j] = __builtin_amdgcn_mfma_f32_16x16x32_bf16(af[i], bf[j], acc[i][j], 0, 0, 0);
    }

    #pragma unroll
    for (int j = 0; j < 2; j++) {
        int col = nb + wx * 32 + j * 16 + l16;
        float bval = bp[col];
        #pragma unroll
        for (int i = 0; i < 4; i++) {
            #pragma unroll
            for (int r = 0; r < 4; r++) {
                int row = mb + wy * 64 + i * 16 + quad * 4 + r;
                out[(size_t)row * DIM + col] = acc[i][j][r] + bval;
            }
        }
    }
}

// ---------------------------------------------------------------------------
extern "C" void kernel_launch(void* const* d_in, const int* in_sizes, int n_in,
                              void* d_out, int out_size, void* d_ws, size_t ws_size,
                              hipStream_t stream) {
    const float* x   = (const float*)d_in[0];
    const float* Wq  = (const float*)d_in[1];
    const float* bq  = (const float*)d_in[2];
    const float* Wk  = (const float*)d_in[3];
    const float* bk  = (const float*)d_in[4];
    const float* Wv  = (const float*)d_in[5];
    const float* bv  = (const float*)d_in[6];
    const float* Wp  = (const float*)d_in[7];
    const float* bp  = (const float*)d_in[8];
    const float* rph = (const float*)d_in[9];
    const float* rpw = (const float*)d_in[10];
    const float* Aq  = (const float*)d_in[11];
    const float* Bq  = (const float*)d_in[12];
    const float* Ak  = (const float*)d_in[13];
    const float* Bk  = (const float*)d_in[14];
    const float* Av  = (const float*)d_in[15];
    const float* Bv  = (const float*)d_in[16];
    float* out = (float*)d_out;

    char* w = (char*)d_ws;
    size_t off = 0;
    auto carve = [&](size_t bytes) {
        char* p = w + off;
        off += (bytes + 255) & ~(size_t)255;
        return p;
    };
    ushort_t* xb    = (ushort_t*)carve((size_t)NTOK * DIM * 2);
    ushort_t* WT    = (ushort_t*)carve((size_t)4 * DIM * DIM * 2);
    ushort_t* Qb    = (ushort_t*)carve((size_t)HEADS * NTOK * HD * 2);
    ushort_t* Kb    = (ushort_t*)carve((size_t)HEADS * NTOK * HD * 2);
    ushort_t* Vtb   = (ushort_t*)carve((size_t)HEADS * HD * NTOK * 2);
    float*    relH  = (float*)carve((size_t)HEADS * NTOK * GRD * 4);
    float*    relW  = (float*)carve((size_t)HEADS * NTOK * GRD * 4);
    ushort_t* Ob    = (ushort_t*)carve((size_t)NTOK * DIM * 2);
    float*    Opart = (float*)carve((size_t)CHUNKS * HEADS * NTOK * HD * 4);
    float*    Lpart = (float*)carve((size_t)CHUNKS * HEADS * NTOK * 4);
    ushort_t* rphb  = (ushort_t*)carve((size_t)(2 * GRD - 1) * HD * 2);
    ushort_t* rpwb  = (ushort_t*)carve((size_t)(2 * GRD - 1) * HD * 2);

    k_prep<<<dim3(2304), dim3(256), 0, stream>>>(
        x, xb, rph, rpw, rphb, rpwb,
        Wq, Wk, Wv, Wp, Aq, Bq, Ak, Bk, Av, Bv, WT);
    k_gemm_qkv<<<dim3(36, 18), dim3(256), 0, stream>>>(
        xb, WT, bq, bk, bv, Qb, Kb, Vtb);
    k_relmm<<<dim3(288), dim3(256), 0, stream>>>(
        Qb, rphb, rpwb, relH, relW);
    k_attn<<<dim3(HEADS * CHUNKS, NTOK / 128), dim3(256), 0, stream>>>(
        Qb, Kb, Vtb, relH, relW, Opart, Lpart);
    k_merge<<<dim3(HEADS * NTOK * HD / (256 * 4)), dim3(256), 0, stream>>>(
        Opart, Lpart, Ob);
    k_gemm_proj<<<dim3(12, 18), dim3(256), 0, stream>>>(
        Ob, WT + (size_t)3 * DIM * DIM, bp, out);
}